// Round 3
// baseline (289.749 us; speedup 1.0000x reference)
//
#include <hip/hip_runtime.h>
#include <math.h>

// Problem constants
#define H   2048
#define NB  8192
#define KCH 64          // chunks along H
#define LCH 32          // steps per chunk (H / KCH)
#define BPC 8           // blocks per chunk (NB / 1024); each block covers 1024 rollouts (256 thr x 4)

// Model constants: DT = 0.05, WHEELBASE = 2.5, MAX_STEER = 0.5, MAX_ACC = 5.0
#define DT_F 0.05f

static_assert(KCH * LCH == H, "chunking must cover H");
static_assert(BPC * 1024 == NB, "b-tiling must cover NB");

// Native clang vector type: required for __builtin_nontemporal_store
// (HIP's float4 is a class and is rejected by the builtin).
typedef float f32x4 __attribute__((ext_vector_type(4)));

// ---------------------------------------------------------------------------
// Kernel A: per-step constant scans. 1024 threads x 2 elems so the 2048
// double tans spread over 16 waves instead of 4.
//   dv_j = DT*MAX_ACC*clip(a_j, -1, 1)
//   w_j  = (DT/WHEELBASE)*tan(clip(s_j, -0.5, 0.5))
//   C_i  = exclusive prefix of dv   (speed_i = s0 + C_i)
//   A_i  = exclusive prefix of w    (yaw_i = yaw0 + s0*A_i + B_i)
//   B_i  = exclusive prefix of C_j*w_j
// Double-precision accumulation; controls index j runs 0..H-2 (last unused).
// ---------------------------------------------------------------------------
__global__ __launch_bounds__(1024) void precomp_scan(
    const float* __restrict__ accel, const float* __restrict__ steering,
    float* __restrict__ Cv, float* __restrict__ Av, float* __restrict__ Bv) {
  __shared__ double l1[1024];
  __shared__ double l2[1024];
  const int t = threadIdx.x;

  double dv[2], w[2], Cl[2];
  for (int m = 0; m < 2; ++m) {
    int j = t * 2 + m;
    if (j < H - 1) {
      float a = accel[j];    a = fminf(1.0f, fmaxf(-1.0f, a));
      float s = steering[j]; s = fminf(0.5f, fmaxf(-0.5f, s));
      dv[m] = 0.25 * (double)a;          // DT * MAX_ACC = 0.05 * 5.0
      w[m]  = 0.02 * tan((double)s);     // DT / WHEELBASE = 0.05 / 2.5
    } else {
      dv[m] = 0.0; w[m] = 0.0;
    }
  }

  // --- fused scans 1 & 2: dv -> C, w -> A (both exclusive) ---
  {
    double tot1 = dv[0] + dv[1];
    double tot2 = w[0] + w[1];
    double run1 = tot1, run2 = tot2;
    l1[t] = run1; l2[t] = run2; __syncthreads();
    for (int off = 1; off < 1024; off <<= 1) {
      double y1 = (t >= off) ? l1[t - off] : 0.0;
      double y2 = (t >= off) ? l2[t - off] : 0.0;
      __syncthreads();
      run1 += y1; run2 += y2;
      l1[t] = run1; l2[t] = run2; __syncthreads();
    }
    double e1 = run1 - tot1;   // exclusive base for dv
    double e2 = run2 - tot2;   // exclusive base for w
    Cl[0] = e1; Cv[t * 2] = (float)e1; Av[t * 2] = (float)e2;
    e1 += dv[0]; e2 += w[0];
    Cl[1] = e1; Cv[t * 2 + 1] = (float)e1; Av[t * 2 + 1] = (float)e2;
  }
  __syncthreads();

  // --- scan 3: C*w -> B (exclusive) ---
  {
    double v0 = Cl[0] * w[0];
    double v1 = Cl[1] * w[1];
    double tot = v0 + v1;
    double run = tot;
    l1[t] = run; __syncthreads();
    for (int off = 1; off < 1024; off <<= 1) {
      double y = (t >= off) ? l1[t - off] : 0.0;
      __syncthreads();
      run += y; l1[t] = run; __syncthreads();
    }
    double e = run - tot;
    Bv[t * 2] = (float)e; e += v0;
    Bv[t * 2 + 1] = (float)e;
  }
}

// ---------------------------------------------------------------------------
// Kernel B: closed-form yaw/speed outputs + per-chunk partials of
// speed*cos(yaw), speed*sin(yaw). Each thread owns 4 consecutive rollouts so
// output stores are global_store_dwordx4 (16 B/lane, nontemporal).
// Grid: KCH * BPC blocks of 256.
// ---------------------------------------------------------------------------
__global__ __launch_bounds__(256) void yaw_speed_partials(
    const float* __restrict__ syaw, const float* __restrict__ sspd,
    const float* __restrict__ Cv, const float* __restrict__ Av,
    const float* __restrict__ Bv,
    float* __restrict__ out, float* __restrict__ px, float* __restrict__ py) {
  __shared__ float sC[LCH], sA[LCH], sB[LCH];
  const int k  = blockIdx.x >> 3;                       // / BPC
  const int b  = ((blockIdx.x & (BPC - 1)) << 10) + (threadIdx.x << 2);
  const int j0 = k * LCH;
  if (threadIdx.x < LCH) {
    sC[threadIdx.x] = Cv[j0 + threadIdx.x];
    sA[threadIdx.x] = Av[j0 + threadIdx.x];
    sB[threadIdx.x] = Bv[j0 + threadIdx.x];
  }
  __syncthreads();

  const f32x4 yaw0v = *(const f32x4*)(syaw + b);
  const f32x4 s0v   = *(const f32x4*)(sspd + b);
  float yaw0[4] = {yaw0v.x, yaw0v.y, yaw0v.z, yaw0v.w};
  float s0[4]   = {s0v.x, s0v.y, s0v.z, s0v.w};
  float accx[4] = {0.f, 0.f, 0.f, 0.f};
  float accy[4] = {0.f, 0.f, 0.f, 0.f};
  float* __restrict__ oy = out + 2 * (size_t)H * NB;
  float* __restrict__ os = out + 3 * (size_t)H * NB;

  for (int m = 0; m < LCH; ++m) {
    const float C  = sC[m];
    const float A  = sA[m];
    const float Bc = sB[m];
    float spd[4], yw[4], sn[4], cs[4];
#pragma unroll
    for (int q = 0; q < 4; ++q) {
      spd[q] = s0[q] + C;
      yw[q]  = fmaf(s0[q], A, yaw0[q]) + Bc;
      __sincosf(yw[q], &sn[q], &cs[q]);
    }
    const size_t idx = (size_t)(j0 + m) * NB + b;
    f32x4 ywv, spdv;
    ywv.x = yw[0]; ywv.y = yw[1]; ywv.z = yw[2]; ywv.w = yw[3];
    spdv.x = spd[0]; spdv.y = spd[1]; spdv.z = spd[2]; spdv.w = spd[3];
    __builtin_nontemporal_store(ywv,  (f32x4*)(oy + idx));
    __builtin_nontemporal_store(spdv, (f32x4*)(os + idx));
#pragma unroll
    for (int q = 0; q < 4; ++q) {
      accx[q] = fmaf(spd[q], cs[q], accx[q]);
      accy[q] = fmaf(spd[q], sn[q], accy[q]);
    }
  }
  f32x4 axv, ayv;
  axv.x = accx[0]; axv.y = accx[1]; axv.z = accx[2]; axv.w = accx[3];
  ayv.x = accy[0]; ayv.y = accy[1]; ayv.z = accy[2]; ayv.w = accy[3];
  *(f32x4*)(px + (size_t)k * NB + b) = axv;
  *(f32x4*)(py + (size_t)k * NB + b) = ayv;
}

// ---------------------------------------------------------------------------
// Kernel C: exclusive scan over KCH chunk partials, per rollout.
// ---------------------------------------------------------------------------
__global__ __launch_bounds__(256) void chunk_scan(
    const float* __restrict__ px, const float* __restrict__ py,
    float* __restrict__ ox, float* __restrict__ oyv) {
  const int b = blockIdx.x * 256 + threadIdx.x;
  float ax = 0.0f, ay = 0.0f;
  for (int k = 0; k < KCH; ++k) {
    float tx = px[(size_t)k * NB + b];
    float ty = py[(size_t)k * NB + b];
    ox[(size_t)k * NB + b]  = ax;
    oyv[(size_t)k * NB + b] = ay;
    ax += tx;
    ay += ty;
  }
}

// ---------------------------------------------------------------------------
// Kernel D: x/y outputs, vec4 along rollouts. Running prefix starts at the
// chunk offset; within the chunk, re-derive speed/yaw closed-form and
// recompute sincos (cheaper than 134 MB extra HBM traffic).
// ---------------------------------------------------------------------------
__global__ __launch_bounds__(256) void xy_write(
    const float* __restrict__ sx, const float* __restrict__ sy,
    const float* __restrict__ syaw, const float* __restrict__ sspd,
    const float* __restrict__ Cv, const float* __restrict__ Av,
    const float* __restrict__ Bv,
    const float* __restrict__ ox, const float* __restrict__ oyv,
    float* __restrict__ out) {
  __shared__ float sC[LCH], sA[LCH], sB[LCH];
  const int k  = blockIdx.x >> 3;
  const int b  = ((blockIdx.x & (BPC - 1)) << 10) + (threadIdx.x << 2);
  const int j0 = k * LCH;
  if (threadIdx.x < LCH) {
    sC[threadIdx.x] = Cv[j0 + threadIdx.x];
    sA[threadIdx.x] = Av[j0 + threadIdx.x];
    sB[threadIdx.x] = Bv[j0 + threadIdx.x];
  }
  __syncthreads();

  const f32x4 x0v   = *(const f32x4*)(sx + b);
  const f32x4 y0v   = *(const f32x4*)(sy + b);
  const f32x4 yaw0v = *(const f32x4*)(syaw + b);
  const f32x4 s0v   = *(const f32x4*)(sspd + b);
  const f32x4 rxv   = *(const f32x4*)(ox  + (size_t)k * NB + b);
  const f32x4 ryv   = *(const f32x4*)(oyv + (size_t)k * NB + b);
  float x0[4]   = {x0v.x, x0v.y, x0v.z, x0v.w};
  float y0[4]   = {y0v.x, y0v.y, y0v.z, y0v.w};
  float yaw0[4] = {yaw0v.x, yaw0v.y, yaw0v.z, yaw0v.w};
  float s0[4]   = {s0v.x, s0v.y, s0v.z, s0v.w};
  float rx[4]   = {rxv.x, rxv.y, rxv.z, rxv.w};
  float ry[4]   = {ryv.x, ryv.y, ryv.z, ryv.w};
  float* __restrict__ outx = out;
  float* __restrict__ outy = out + (size_t)H * NB;

  for (int m = 0; m < LCH; ++m) {
    const float C  = sC[m];
    const float A  = sA[m];
    const float Bc = sB[m];
    float spd[4], yw[4], sn[4], cs[4], wx[4], wy[4];
#pragma unroll
    for (int q = 0; q < 4; ++q) {
      spd[q] = s0[q] + C;
      yw[q]  = fmaf(s0[q], A, yaw0[q]) + Bc;
      __sincosf(yw[q], &sn[q], &cs[q]);
      wx[q] = fmaf(DT_F, rx[q], x0[q]);
      wy[q] = fmaf(DT_F, ry[q], y0[q]);
    }
    const size_t idx = (size_t)(j0 + m) * NB + b;
    f32x4 wxv, wyv;
    wxv.x = wx[0]; wxv.y = wx[1]; wxv.z = wx[2]; wxv.w = wx[3];
    wyv.x = wy[0]; wyv.y = wy[1]; wyv.z = wy[2]; wyv.w = wy[3];
    __builtin_nontemporal_store(wxv, (f32x4*)(outx + idx));
    __builtin_nontemporal_store(wyv, (f32x4*)(outy + idx));
#pragma unroll
    for (int q = 0; q < 4; ++q) {
      rx[q] = fmaf(spd[q], cs[q], rx[q]);
      ry[q] = fmaf(spd[q], sn[q], ry[q]);
    }
  }
}

// ---------------------------------------------------------------------------
extern "C" void kernel_launch(void* const* d_in, const int* in_sizes, int n_in,
                              void* d_out, int out_size, void* d_ws, size_t ws_size,
                              hipStream_t stream) {
  const float* start_x     = (const float*)d_in[0];
  const float* start_y     = (const float*)d_in[1];
  const float* start_yaw   = (const float*)d_in[2];
  const float* start_speed = (const float*)d_in[3];
  const float* accel       = (const float*)d_in[4];
  const float* steering    = (const float*)d_in[5];
  float* out = (float*)d_out;

  // Workspace layout (floats):
  //   [0, H)        C   (speed offsets)
  //   [H, 2H)       A   (yaw slope vs s0)
  //   [2H, 3H)      B   (yaw constant)
  //   then px, py, ox, oy, each KCH*NB
  float* ws = (float*)d_ws;
  float* Cv  = ws;
  float* Av  = ws + H;
  float* Bv  = ws + 2 * H;
  float* px  = ws + 3 * H;
  float* py  = px + (size_t)KCH * NB;
  float* ox  = py + (size_t)KCH * NB;
  float* oyv = ox + (size_t)KCH * NB;

  precomp_scan<<<1, 1024, 0, stream>>>(accel, steering, Cv, Av, Bv);
  yaw_speed_partials<<<KCH * BPC, 256, 0, stream>>>(start_yaw, start_speed,
                                                    Cv, Av, Bv, out, px, py);
  chunk_scan<<<NB / 256, 256, 0, stream>>>(px, py, ox, oyv);
  xy_write<<<KCH * BPC, 256, 0, stream>>>(start_x, start_y, start_yaw, start_speed,
                                          Cv, Av, Bv, ox, oyv, out);
}

// Round 4
// 286.104 us; speedup vs baseline: 1.0127x; 1.0127x over previous
//
#include <hip/hip_runtime.h>
#include <math.h>

// Problem constants
#define H   2048
#define NB  8192
#define KCH 64          // chunks along H
#define LCH 32          // steps per chunk (H / KCH)
#define BPC 8           // blocks per chunk (NB / 1024); each block covers 1024 rollouts (256 thr x 4)

// Model constants: DT = 0.05, WHEELBASE = 2.5, MAX_STEER = 0.5, MAX_ACC = 5.0
#define DT_F 0.05f

static_assert(KCH * LCH == H, "chunking must cover H");
static_assert(BPC * 1024 == NB, "b-tiling must cover NB");

// Native clang vector type: required for __builtin_nontemporal_store
// (HIP's float4 is a class and is rejected by the builtin).
typedef float f32x4 __attribute__((ext_vector_type(4)));

// ---------------------------------------------------------------------------
// Kernel A: per-step constant scans, shfl-based (4 barriers vs 20 in the LDS
// ladder). 1024 threads x 2 elems.
//   dv_j = DT*MAX_ACC*clip(a_j, -1, 1)
//   w_j  = (DT/WHEELBASE)*tan(clip(s_j, -0.5, 0.5))
//   C_i  = exclusive prefix of dv   (speed_i = s0 + C_i)
//   A_i  = exclusive prefix of w    (yaw_i = yaw0 + s0*A_i + B_i)
//   B_i  = exclusive prefix of C_j*w_j
// Double-precision accumulation; controls index j runs 0..H-2 (last unused).
// ---------------------------------------------------------------------------
__global__ __launch_bounds__(1024) void precomp_scan(
    const float* __restrict__ accel, const float* __restrict__ steering,
    float* __restrict__ Cv, float* __restrict__ Av, float* __restrict__ Bv) {
  __shared__ double wsum1[16], wsum2[16];
  __shared__ double woff1[16], woff2[16];
  const int t    = threadIdx.x;
  const int lane = t & 63;
  const int wid  = t >> 6;          // 16 waves

  double dv[2], w[2];
  for (int m = 0; m < 2; ++m) {
    int j = t * 2 + m;
    if (j < H - 1) {
      float a = accel[j];    a = fminf(1.0f, fmaxf(-1.0f, a));
      float s = steering[j]; s = fminf(0.5f, fmaxf(-0.5f, s));
      dv[m] = 0.25 * (double)a;          // DT * MAX_ACC = 0.05 * 5.0
      w[m]  = 0.02 * tan((double)s);     // DT / WHEELBASE = 0.05 / 2.5
    } else {
      dv[m] = 0.0; w[m] = 0.0;
    }
  }

  // --- stage 1: dual scan {dv -> C, w -> A}, exclusive ---
  double p1 = dv[0] + dv[1];
  double p2 = w[0] + w[1];
  double i1 = p1, i2 = p2;               // inclusive wave scan over pair-sums
  for (int off = 1; off < 64; off <<= 1) {
    double u1 = __shfl_up(i1, (unsigned)off);
    double u2 = __shfl_up(i2, (unsigned)off);
    if (lane >= off) { i1 += u1; i2 += u2; }
  }
  if (lane == 63) { wsum1[wid] = i1; wsum2[wid] = i2; }
  __syncthreads();
  if (wid == 0) {
    double v1 = (lane < 16) ? wsum1[lane] : 0.0;
    double v2 = (lane < 16) ? wsum2[lane] : 0.0;
    double s1 = v1, s2 = v2;
    for (int off = 1; off < 16; off <<= 1) {
      double u1 = __shfl_up(s1, (unsigned)off);
      double u2 = __shfl_up(s2, (unsigned)off);
      if (lane >= off) { s1 += u1; s2 += u2; }
    }
    if (lane < 16) { woff1[lane] = s1 - v1; woff2[lane] = s2 - v2; }
  }
  __syncthreads();
  double e1 = woff1[wid] + (i1 - p1);    // exclusive base for elem 2t
  double e2 = woff2[wid] + (i2 - p2);
  double C0 = e1,          A0 = e2;
  double C1 = e1 + dv[0],  A1 = e2 + w[0];
  Cv[t * 2]     = (float)C0;  Av[t * 2]     = (float)A0;
  Cv[t * 2 + 1] = (float)C1;  Av[t * 2 + 1] = (float)A1;

  // --- stage 2: scan C*w -> B, exclusive ---
  double v0 = C0 * w[0];
  double v1 = C1 * w[1];
  double p3 = v0 + v1;
  double i3 = p3;
  for (int off = 1; off < 64; off <<= 1) {
    double u3 = __shfl_up(i3, (unsigned)off);
    if (lane >= off) i3 += u3;
  }
  if (lane == 63) wsum1[wid] = i3;
  __syncthreads();
  if (wid == 0) {
    double v3 = (lane < 16) ? wsum1[lane] : 0.0;
    double s3 = v3;
    for (int off = 1; off < 16; off <<= 1) {
      double u3 = __shfl_up(s3, (unsigned)off);
      if (lane >= off) s3 += u3;
    }
    if (lane < 16) woff1[lane] = s3 - v3;
  }
  __syncthreads();
  double e3 = woff1[wid] + (i3 - p3);
  Bv[t * 2]     = (float)e3;
  Bv[t * 2 + 1] = (float)(e3 + v0);
}

// ---------------------------------------------------------------------------
// Kernel B: closed-form yaw/speed outputs + per-chunk partials of
// speed*cos(yaw), speed*sin(yaw). Each thread owns 4 consecutive rollouts so
// output stores are global_store_dwordx4 (16 B/lane, nontemporal). Partials
// are written PACKED as float2 (x,y) per rollout, so kernel C can stream
// them with half the memory instructions.
// Grid: KCH * BPC blocks of 256.
// ---------------------------------------------------------------------------
__global__ __launch_bounds__(256) void yaw_speed_partials(
    const float* __restrict__ syaw, const float* __restrict__ sspd,
    const float* __restrict__ Cv, const float* __restrict__ Av,
    const float* __restrict__ Bv,
    float* __restrict__ out, float2* __restrict__ pxy) {
  __shared__ float sC[LCH], sA[LCH], sB[LCH];
  const int k  = blockIdx.x >> 3;                       // / BPC
  const int b  = ((blockIdx.x & (BPC - 1)) << 10) + (threadIdx.x << 2);
  const int j0 = k * LCH;
  if (threadIdx.x < LCH) {
    sC[threadIdx.x] = Cv[j0 + threadIdx.x];
    sA[threadIdx.x] = Av[j0 + threadIdx.x];
    sB[threadIdx.x] = Bv[j0 + threadIdx.x];
  }
  __syncthreads();

  const f32x4 yaw0v = *(const f32x4*)(syaw + b);
  const f32x4 s0v   = *(const f32x4*)(sspd + b);
  float yaw0[4] = {yaw0v.x, yaw0v.y, yaw0v.z, yaw0v.w};
  float s0[4]   = {s0v.x, s0v.y, s0v.z, s0v.w};
  float accx[4] = {0.f, 0.f, 0.f, 0.f};
  float accy[4] = {0.f, 0.f, 0.f, 0.f};
  float* __restrict__ oy = out + 2 * (size_t)H * NB;
  float* __restrict__ os = out + 3 * (size_t)H * NB;

  for (int m = 0; m < LCH; ++m) {
    const float C  = sC[m];
    const float A  = sA[m];
    const float Bc = sB[m];
    float spd[4], yw[4], sn[4], cs[4];
#pragma unroll
    for (int q = 0; q < 4; ++q) {
      spd[q] = s0[q] + C;
      yw[q]  = fmaf(s0[q], A, yaw0[q]) + Bc;
      __sincosf(yw[q], &sn[q], &cs[q]);
    }
    const size_t idx = (size_t)(j0 + m) * NB + b;
    f32x4 ywv, spdv;
    ywv.x = yw[0]; ywv.y = yw[1]; ywv.z = yw[2]; ywv.w = yw[3];
    spdv.x = spd[0]; spdv.y = spd[1]; spdv.z = spd[2]; spdv.w = spd[3];
    __builtin_nontemporal_store(ywv,  (f32x4*)(oy + idx));
    __builtin_nontemporal_store(spdv, (f32x4*)(os + idx));
#pragma unroll
    for (int q = 0; q < 4; ++q) {
      accx[q] = fmaf(spd[q], cs[q], accx[q]);
      accy[q] = fmaf(spd[q], sn[q], accy[q]);
    }
  }
  // packed partial store: [x0 y0 x1 y1][x2 y2 x3 y3]
  f32x4 p01, p23;
  p01.x = accx[0]; p01.y = accy[0]; p01.z = accx[1]; p01.w = accy[1];
  p23.x = accx[2]; p23.y = accy[2]; p23.z = accx[3]; p23.w = accy[3];
  f32x4* pp = (f32x4*)(pxy + (size_t)k * NB + b);
  pp[0] = p01;
  pp[1] = p23;
}

// ---------------------------------------------------------------------------
// Kernel C: exclusive scan over KCH=64 chunk partials, per rollout.
// 128 blocks x 256 threads: 4 threads per rollout, each owning 16 chunks
// kept in registers (independent loads -> latency hidden), quarter sums
// combined through one LDS round.
// ---------------------------------------------------------------------------
__global__ __launch_bounds__(256) void chunk_scan(
    const float2* __restrict__ pxy, float2* __restrict__ oxy) {
  __shared__ float sx_[4][64];
  __shared__ float sy_[4][64];
  const int q = threadIdx.x >> 6;            // quarter 0..3 (chunks 16q..16q+15)
  const int i = threadIdx.x & 63;
  const int b = blockIdx.x * 64 + i;         // rollout

  float vx[16], vy[16];
  float ax = 0.f, ay = 0.f;
#pragma unroll
  for (int kk = 0; kk < 16; ++kk) {
    const int k = q * 16 + kk;
    float2 v = pxy[(size_t)k * NB + b];
    vx[kk] = v.x; vy[kk] = v.y;
    ax += v.x; ay += v.y;
  }
  sx_[q][i] = ax; sy_[q][i] = ay;
  __syncthreads();

  float ox = 0.f, oy = 0.f;
  for (int qq = 0; qq < q; ++qq) { ox += sx_[qq][i]; oy += sy_[qq][i]; }

#pragma unroll
  for (int kk = 0; kk < 16; ++kk) {
    const int k = q * 16 + kk;
    float2 o; o.x = ox; o.y = oy;
    oxy[(size_t)k * NB + b] = o;
    ox += vx[kk]; oy += vy[kk];
  }
}

// ---------------------------------------------------------------------------
// Kernel D: x/y outputs, vec4 along rollouts. Running prefix starts at the
// chunk offset (packed float2); within the chunk, re-derive speed/yaw in
// closed form and recompute sincos (cheaper than 134 MB extra HBM traffic).
// ---------------------------------------------------------------------------
__global__ __launch_bounds__(256) void xy_write(
    const float* __restrict__ sx, const float* __restrict__ sy,
    const float* __restrict__ syaw, const float* __restrict__ sspd,
    const float* __restrict__ Cv, const float* __restrict__ Av,
    const float* __restrict__ Bv,
    const float2* __restrict__ oxy,
    float* __restrict__ out) {
  __shared__ float sC[LCH], sA[LCH], sB[LCH];
  const int k  = blockIdx.x >> 3;
  const int b  = ((blockIdx.x & (BPC - 1)) << 10) + (threadIdx.x << 2);
  const int j0 = k * LCH;
  if (threadIdx.x < LCH) {
    sC[threadIdx.x] = Cv[j0 + threadIdx.x];
    sA[threadIdx.x] = Av[j0 + threadIdx.x];
    sB[threadIdx.x] = Bv[j0 + threadIdx.x];
  }
  __syncthreads();

  const f32x4 x0v   = *(const f32x4*)(sx + b);
  const f32x4 y0v   = *(const f32x4*)(sy + b);
  const f32x4 yaw0v = *(const f32x4*)(syaw + b);
  const f32x4 s0v   = *(const f32x4*)(sspd + b);
  const f32x4* op   = (const f32x4*)(oxy + (size_t)k * NB + b);
  const f32x4 o01 = op[0];   // [x0 y0 x1 y1]
  const f32x4 o23 = op[1];   // [x2 y2 x3 y3]
  float x0[4]   = {x0v.x, x0v.y, x0v.z, x0v.w};
  float y0[4]   = {y0v.x, y0v.y, y0v.z, y0v.w};
  float yaw0[4] = {yaw0v.x, yaw0v.y, yaw0v.z, yaw0v.w};
  float s0[4]   = {s0v.x, s0v.y, s0v.z, s0v.w};
  float rx[4]   = {o01.x, o01.z, o23.x, o23.z};
  float ry[4]   = {o01.y, o01.w, o23.y, o23.w};
  float* __restrict__ outx = out;
  float* __restrict__ outy = out + (size_t)H * NB;

  for (int m = 0; m < LCH; ++m) {
    const float C  = sC[m];
    const float A  = sA[m];
    const float Bc = sB[m];
    float spd[4], yw[4], sn[4], cs[4], wx[4], wy[4];
#pragma unroll
    for (int q = 0; q < 4; ++q) {
      spd[q] = s0[q] + C;
      yw[q]  = fmaf(s0[q], A, yaw0[q]) + Bc;
      __sincosf(yw[q], &sn[q], &cs[q]);
      wx[q] = fmaf(DT_F, rx[q], x0[q]);
      wy[q] = fmaf(DT_F, ry[q], y0[q]);
    }
    const size_t idx = (size_t)(j0 + m) * NB + b;
    f32x4 wxv, wyv;
    wxv.x = wx[0]; wxv.y = wx[1]; wxv.z = wx[2]; wxv.w = wx[3];
    wyv.x = wy[0]; wyv.y = wy[1]; wyv.z = wy[2]; wyv.w = wy[3];
    __builtin_nontemporal_store(wxv, (f32x4*)(outx + idx));
    __builtin_nontemporal_store(wyv, (f32x4*)(outy + idx));
#pragma unroll
    for (int q = 0; q < 4; ++q) {
      rx[q] = fmaf(spd[q], cs[q], rx[q]);
      ry[q] = fmaf(spd[q], sn[q], ry[q]);
    }
  }
}

// ---------------------------------------------------------------------------
extern "C" void kernel_launch(void* const* d_in, const int* in_sizes, int n_in,
                              void* d_out, int out_size, void* d_ws, size_t ws_size,
                              hipStream_t stream) {
  const float* start_x     = (const float*)d_in[0];
  const float* start_y     = (const float*)d_in[1];
  const float* start_yaw   = (const float*)d_in[2];
  const float* start_speed = (const float*)d_in[3];
  const float* accel       = (const float*)d_in[4];
  const float* steering    = (const float*)d_in[5];
  float* out = (float*)d_out;

  // Workspace layout (floats):
  //   [0, H)        C   (speed offsets)
  //   [H, 2H)       A   (yaw slope vs s0)
  //   [2H, 3H)      B   (yaw constant)
  //   [3H, 4H)      pad (keeps pxy 16B-aligned)
  //   then pxy (packed float2, KCH*NB), oxy (packed float2, KCH*NB)
  float* ws = (float*)d_ws;
  float* Cv  = ws;
  float* Av  = ws + H;
  float* Bv  = ws + 2 * H;
  float2* pxy = (float2*)(ws + 4 * H);
  float2* oxy = pxy + (size_t)KCH * NB;

  precomp_scan<<<1, 1024, 0, stream>>>(accel, steering, Cv, Av, Bv);
  yaw_speed_partials<<<KCH * BPC, 256, 0, stream>>>(start_yaw, start_speed,
                                                    Cv, Av, Bv, out, pxy);
  chunk_scan<<<NB / 64, 256, 0, stream>>>(pxy, oxy);
  xy_write<<<KCH * BPC, 256, 0, stream>>>(start_x, start_y, start_yaw, start_speed,
                                          Cv, Av, Bv, oxy, out);
}